// Round 7
// baseline (178.409 us; speedup 1.0000x reference)
//
#include <hip/hip_runtime.h>

// out[p][f] = sum_s x[p][s] * K[s][f];  P = 393,216, K 64x64 fp32.
//
// R11: six nulls (R5-R10, all 59.4-65.5us) -- but R9/R10's failure exposes
// the untested axis: per-wave VMEM QUEUE ORDER. vmcnt is one in-order
// counter; every rolling pipeline issues next-tile loads AFTER prior-tile
// stores, so any load-wait transitively forces older stores retired ->
// effective outstanding collapses to ~1KB/wave (measured 4.1 B/cy/CU).
// Fix: LOAD-FIRST burst. All 12 tile-loads issued in one burst before ANY
// store enters the queue (sched_barrier(0) pins issue order). Then no
// load-wait can ever drain a store; stores retire fully async. Constant
// wait per tile s: remaining loads (2-s)*4 + prior stores 4s = vmcnt(8).
//   * 2048 blk x 4 waves x 3 tiles (exact); data in regs (48 VGPR), no
//     x-LDS; K overlaid in transpose scratch -> LDS 17.4KB; ~16 waves/CU
//     -> 48KB outstanding reads/CU (3x R9).
//   * store path: R8b-verified LDS transpose -> 4x contiguous nt dwordx4
//     (WRITE=98MB clean).
// Numerics unchanged (3-term bf16 hi/lo, absmax 0.03125).
// Prediction: dur 59.5 -> 30-42us, hbm 2.5 -> >=4 TB/s, WRITE ~98MB,
// FETCH ~49MB. PRE-COMMIT: if null (57-63us), 7 concordant nulls across
// every structural axis -> declare ROOFLINE.

#define THREADS 256
#define WPB     4
#define NT      3           // tiles/wave; 2048 blk * 4 * 3 = 24576 exact
#define OROW    68          // transpose scratch row stride (floats)

typedef __attribute__((ext_vector_type(8))) short bf16x8;
typedef __attribute__((ext_vector_type(4))) float f32x4;

static __device__ __forceinline__ unsigned short bf16_rne(float f) {
    unsigned int u = __float_as_uint(f);
    u += 0x7fffu + ((u >> 16) & 1u);
    return (unsigned short)(u >> 16);
}
static __device__ __forceinline__ float bf16f(unsigned short h) {
    return __uint_as_float((unsigned int)h << 16);
}

__global__ __launch_bounds__(THREADS)
void dct_kernel(const float* __restrict__ x,
                const float* __restrict__ Kmat,
                float* __restrict__ out) {
    __shared__ __align__(16) float oscr[WPB][16][OROW];   // 17.4 KB
    // K staging overlays oscr (prologue only, fenced by barriers)
    short* bhi = (short*)&oscr[0][0][0];
    short* blo = bhi + 8 * 64 * 8;

    const int tid  = threadIdx.x;
    const int lane = tid & 63;
    const int wv   = tid >> 6;
    const int l15  = lane & 15;
    const int quad = lane >> 4;

    const int totw = (int)gridDim.x * WPB;              // 8192 waves
    const long long wt0 = (long long)blockIdx.x * WPB + wv;
    const f32x4* src = (const f32x4*)x + wt0 * 256;     // tile base (float4)
    const long long TS4 = (long long)totw * 256;        // float4 step per s
    float* dst = out + wt0 * 1024;
    const long long SSTEP = (long long)totw * 1024;     // float step per s

    // ---- LOAD-FIRST BURST: all 3 tiles (12x dwordx4, 3KB/wave) ----
    // reg (t,i): tile t bytes [i*1024 + lane*16) -> row i*4+quad, col l15*4
    f32x4 cc[NT][4];
#pragma unroll
    for (int t = 0; t < NT; ++t)
#pragma unroll
        for (int i = 0; i < 4; ++i)
            cc[t][i] = src[(long long)t * TS4 + i * 64 + lane];
    // pin queue order: nothing (especially stores) may be hoisted above,
    // and these loads may not be sunk below.
    __builtin_amdgcn_sched_barrier(0);

    // ---- build K bf16 hi/lo B-frags (overlay); wave wv: combos 2wv,2wv+1 --
#pragma unroll
    for (int ccx = 0; ccx < 2; ++ccx) {
        const int combo = wv * 2 + ccx;
        const int kc = combo >> 2, ft = combo & 3;
        short hh[8], ll[8];
#pragma unroll
        for (int j = 0; j < 8; ++j) {
            float v = Kmat[(kc * 32 + quad * 8 + j) * 64 + ft * 16 + l15];
            unsigned short h = bf16_rne(v);
            hh[j] = (short)h;
            ll[j] = (short)bf16_rne(v - bf16f(h));
        }
        *(bf16x8*)&bhi[(combo * 64 + lane) * 8] = *(bf16x8*)hh;
        *(bf16x8*)&blo[(combo * 64 + lane) * 8] = *(bf16x8*)ll;
    }
    __syncthreads();

    bf16x8 Bh[8], Bl[8];
#pragma unroll
    for (int c = 0; c < 8; ++c) {
        Bh[c] = *(const bf16x8*)&bhi[(c * 64 + lane) * 8];
        Bl[c] = *(const bf16x8*)&blo[(c * 64 + lane) * 8];
    }
    __syncthreads();   // overlay reads done before oscr reuse

    // ---- 3 unrolled iterations; loads are ALL older than ALL stores ----
#pragma unroll
    for (int s = 0; s < NT; ++s) {
        // tile s ready when (2-s)*4 loads + 4s stores may remain: vmcnt(8).
        // (compiler would emit the same or tighter; explicit for clarity)
        asm volatile("s_waitcnt vmcnt(8)" ::: "memory");

        // A-frags from registers: row of patch l15 lives in cc[s][*] of the
        // lane group; our lane (quad,l15) needs x[p=l15][kc*32+quad*8+j].
        // That element sits in lane (row>>2 ... ) -- NOT register-local.
        // -> stage through wave-private oscr (same path as epilogue, in
        // reverse): write reg layout, read frag layout. 2-way banks, free.
#pragma unroll
        for (int i = 0; i < 4; ++i)
            *(f32x4*)&oscr[wv][i * 4 + quad][l15 * 4] = cc[s][i];
        // same-wave DS round-trip (in-order, no barrier)
        bf16x8 Ahi[2], Alo[2];
#pragma unroll
        for (int kc = 0; kc < 2; ++kc) {
            const float* ap = &oscr[wv][l15][kc * 32 + quad * 8];
            float av[8];
            *(f32x4*)&av[0] = *(const f32x4*)ap;
            *(f32x4*)&av[4] = *(const f32x4*)(ap + 4);
            short ah[8], al[8];
#pragma unroll
            for (int j = 0; j < 8; ++j) {
                unsigned short h = bf16_rne(av[j]);
                ah[j] = (short)h;
                al[j] = (short)bf16_rne(av[j] - bf16f(h));
            }
            Ahi[kc] = *(bf16x8*)ah;
            Alo[kc] = *(bf16x8*)al;
        }

        f32x4 acc[4];
#pragma unroll
        for (int t = 0; t < 4; ++t) acc[t] = (f32x4){0.f, 0.f, 0.f, 0.f};
#pragma unroll
        for (int kc = 0; kc < 2; ++kc)
#pragma unroll
            for (int ft = 0; ft < 4; ++ft) {
                const int c = kc * 4 + ft;
                acc[ft] = __builtin_amdgcn_mfma_f32_16x16x32_bf16(Ahi[kc], Bh[c], acc[ft], 0, 0, 0);
                acc[ft] = __builtin_amdgcn_mfma_f32_16x16x32_bf16(Alo[kc], Bh[c], acc[ft], 0, 0, 0);
                acc[ft] = __builtin_amdgcn_mfma_f32_16x16x32_bf16(Ahi[kc], Bl[c], acc[ft], 0, 0, 0);
            }

        // epilogue: transpose (overwrites this tile's staging -- already
        // consumed; same-wave DS in-order) -> contiguous nt dwordx4
#pragma unroll
        for (int ft = 0; ft < 4; ++ft)
#pragma unroll
            for (int r = 0; r < 4; ++r)
                oscr[wv][quad * 4 + r][ft * 16 + l15] = acc[ft][r];
        float* ob = dst + (long long)s * SSTEP;
#pragma unroll
        for (int i = 0; i < 4; ++i) {
            f32x4 v = *(const f32x4*)&oscr[wv][i * 4 + quad][l15 * 4];
            __builtin_nontemporal_store(v, (f32x4*)(ob + i * 256 + lane * 4));
        }
    }
}

extern "C" void kernel_launch(void* const* d_in, const int* in_sizes, int n_in,
                              void* d_out, int out_size, void* d_ws, size_t ws_size,
                              hipStream_t stream) {
    const float* x = (const float*)d_in[0];   // (8,3,1024,1024) fp32
    const float* K = (const float*)d_in[1];   // (64,64) fp32
    float* out = (float*)d_out;

    const int total = in_sizes[0];            // 25,165,824 floats
    const int num_patches = total / 64;       // 393,216
    const int wave_tiles  = num_patches / 16; // 24,576
    const int blocks = wave_tiles / (WPB * NT);  // 2048, exact

    dct_kernel<<<blocks, THREADS, 0, stream>>>(x, K, out);
}